// Round 10
// baseline (5339.776 us; speedup 1.0000x reference)
//
#include <hip/hip_runtime.h>
#include <cstdint>
#include <cstddef>

#define HDIM 2048
#define NCLS 11
#define NBLK 128
#define NTHR 512                 // 8 waves
#define NPAIR (HDIM / 2)         // 1024 {h0,h1} pairs
// LDS layout: h element e at float index e + 4*(e>>5)  (pad 4 per 32 -> the
// 32-col chunk of lane l starts at 36*l, 16B-aligned, banks 4l%32: conflict-free)
#define LSZ 2304

// Exchange: hpub[2][1024] u64. Each u64 = two f32 h-values whose LOW 8
// MANTISSA BITS are replaced by tag = (gen>>1)&0xFF (RN-rounded; rel err
// <= 2^-16). gen g lives in buffer g&1. With memset 0xFF and steps<=512 the
// (buffer,tag) pair uniquely identifies gen (collision needs g' = g+-512).
// Single-hop: data arrives WITH its readiness tag; one 8B relaxed
// agent-atomic per poll; zero fences anywhere (R6: fences = L2 nukes,
// ~15us/step; R7/R8: >1 outstanding poll per thread = IFC queue congestion).

__global__ void __launch_bounds__(NTHR, 1) lstm_persistent(
    const float* __restrict__ x0,
    const float* __restrict__ Wih,
    const float* __restrict__ Whh,
    const float* __restrict__ bih,
    const float* __restrict__ bhh,
    const float* __restrict__ Wout,
    const float* __restrict__ bout,
    const int* __restrict__ stepsp,
    float* __restrict__ out,
    unsigned long long* __restrict__ hpub0,
    unsigned long long* __restrict__ hpub1)
{
    const int tid  = threadIdx.x;
    const int wave = tid >> 6;          // 0..7
    const int lane = tid & 63;
    const int bid  = blockIdx.x;
    const int e0   = bid * 16 + 2 * wave;   // this wave's two h elements

    __shared__ float hlds[2][LSZ];
    __shared__ float lsm[NCLS];

    // Per-lane weights: 8 rows (2 elems x 4 gates) x 32 cols [32*lane..+32).
    // r = 4*eloc + gate; W-row R(r) = gate*HDIM + (e0 + eloc).
    float4 w4[8][8];
#pragma unroll
    for (int r = 0; r < 8; ++r) {
        const int R = (r & 3) * HDIM + e0 + (r >> 2);
        const float* src = Wih + (size_t)R * HDIM + 32 * lane;
#pragma unroll
        for (int k = 0; k < 8; ++k) w4[r][k] = *(const float4*)(src + 4 * k);
    }
    float bs[8];
#pragma unroll
    for (int r = 0; r < 8; ++r) {
        const int R = (r & 3) * HDIM + e0 + (r >> 2);
        bs[r] = bih[R] + bhh[R];
    }
    float creg0 = 0.f, creg1 = 0.f, hreg0 = 0.f, hreg1 = 0.f;

    const int steps = stepsp[0];
    // staging indices: thread stages pairs q0=tid, q1=tid+NTHR
    const int o0 = 2 * tid + 4 * ((2 * tid) >> 5);
    const int o1 = 2 * (tid + NTHR) + 4 * ((2 * (tid + NTHR)) >> 5);

    for (int t = 0; t < steps; ++t) {
        const int p = t & 1;
        if (t == 0) {
            *(float2*)&hlds[0][o0] = *(const float2*)(x0 + 2 * tid);
            *(float2*)&hlds[0][o1] = *(const float2*)(x0 + 2 * (tid + NTHR));
        } else {
            const unsigned exp8 = ((unsigned)t >> 1) & 0xFFu;
            const unsigned long long* hp = p ? hpub1 : hpub0;
            unsigned long long v0 = __hip_atomic_load(hp + tid,
                __ATOMIC_RELAXED, __HIP_MEMORY_SCOPE_AGENT);
            unsigned long long v1 = __hip_atomic_load(hp + tid + NTHR,
                __ATOMIC_RELAXED, __HIP_MEMORY_SCOPE_AGENT);
            for (;;) {
                const bool r0 = (((unsigned)v0 & 0xFFu) == exp8) &&
                                (((unsigned)(v0 >> 32) & 0xFFu) == exp8);
                const bool r1 = (((unsigned)v1 & 0xFFu) == exp8) &&
                                (((unsigned)(v1 >> 32) & 0xFFu) == exp8);
                if (r0 && r1) break;
                __builtin_amdgcn_s_sleep(1);
                if (!r0) v0 = __hip_atomic_load(hp + tid,
                    __ATOMIC_RELAXED, __HIP_MEMORY_SCOPE_AGENT);
                if (!r1) v1 = __hip_atomic_load(hp + tid + NTHR,
                    __ATOMIC_RELAXED, __HIP_MEMORY_SCOPE_AGENT);
            }
            float2 s0, s1;      // strip tags
            s0.x = __uint_as_float((unsigned)v0 & 0xFFFFFF00u);
            s0.y = __uint_as_float((unsigned)(v0 >> 32) & 0xFFFFFF00u);
            s1.x = __uint_as_float((unsigned)v1 & 0xFFFFFF00u);
            s1.y = __uint_as_float((unsigned)(v1 >> 32) & 0xFFFFFF00u);
            *(float2*)&hlds[p][o0] = s0;
            *(float2*)&hlds[p][o1] = s1;
        }
        __syncthreads();        // sole per-step barrier (hlds double-buffered)

        // dot: 8 rows x 32 cols per lane, h chunk from LDS
        const float* hc = &hlds[p][36 * lane];
        float acc[8];
#pragma unroll
        for (int r = 0; r < 8; ++r) acc[r] = 0.f;
#pragma unroll
        for (int k = 0; k < 8; ++k) {
            const float4 hv = *(const float4*)(hc + 4 * k);
#pragma unroll
            for (int r = 0; r < 8; ++r) {
                acc[r] += w4[r][k].x * hv.x + w4[r][k].y * hv.y
                        + w4[r][k].z * hv.z + w4[r][k].w * hv.w;
            }
        }
        // butterfly: all lanes end with all 8 full row sums
#pragma unroll
        for (int s = 1; s < 64; s <<= 1)
#pragma unroll
            for (int r = 0; r < 8; ++r)
                acc[r] += __shfl_xor(acc[r], s, 64);

        {   // elem 0
            const float gi = acc[0] + bs[0], gf = acc[1] + bs[1];
            const float gg = acc[2] + bs[2], go = acc[3] + bs[3];
            const float si = 1.0f / (1.0f + expf(-gi));
            const float sf = 1.0f / (1.0f + expf(-gf));
            const float so = 1.0f / (1.0f + expf(-go));
            creg0 = sf * creg0 + si * tanhf(gg);
            hreg0 = so * tanhf(creg0);
        }
        {   // elem 1
            const float gi = acc[4] + bs[4], gf = acc[5] + bs[5];
            const float gg = acc[6] + bs[6], go = acc[7] + bs[7];
            const float si = 1.0f / (1.0f + expf(-gi));
            const float sf = 1.0f / (1.0f + expf(-gf));
            const float so = 1.0f / (1.0f + expf(-go));
            creg1 = sf * creg1 + si * tanhf(gg);
            hreg1 = so * tanhf(creg1);
        }

        if (lane == 0) {        // publish fused {2 tagged h} atom
            const unsigned t8 = ((unsigned)(t + 1) >> 1) & 0xFFu;
            const unsigned u0 = ((__float_as_uint(hreg0) + 0x80u) & 0xFFFFFF00u) | t8;
            const unsigned u1 = ((__float_as_uint(hreg1) + 0x80u) & 0xFFFFFF00u) | t8;
            const unsigned long long pk =
                ((unsigned long long)u1 << 32) | (unsigned long long)u0;
            __hip_atomic_store((((t + 1) & 1) ? hpub1 : hpub0) + (bid * 8 + wave),
                               pk, __ATOMIC_RELAXED, __HIP_MEMORY_SCOPE_AGENT);
        }

        if (t == 0) {           // weights -> Wc = W_ih + W_hh for steps >= 1
#pragma unroll
            for (int r = 0; r < 8; ++r) {
                const int R = (r & 3) * HDIM + e0 + (r >> 2);
                const float* src = Whh + (size_t)R * HDIM + 32 * lane;
#pragma unroll
                for (int k = 0; k < 8; ++k) {
                    const float4 v = *(const float4*)(src + 4 * k);
                    w4[r][k].x += v.x; w4[r][k].y += v.y;
                    w4[r][k].z += v.z; w4[r][k].w += v.w;
                }
            }
        }
    }

    // final h and c straight from registers (disjoint across waves/blocks)
    if (lane == 0) {
        out[NCLS + e0]            = hreg0;
        out[NCLS + e0 + 1]        = hreg1;
        out[NCLS + HDIM + e0]     = creg0;
        out[NCLS + HDIM + e0 + 1] = creg1;
    }

    // block 0: gather final h (gen == steps) and run the classifier head
    if (bid == 0) {
        const int sp = steps & 1;
        const unsigned exp8 = ((unsigned)steps >> 1) & 0xFFu;
        const unsigned long long* hp = sp ? hpub1 : hpub0;
        unsigned long long v0 = __hip_atomic_load(hp + tid,
            __ATOMIC_RELAXED, __HIP_MEMORY_SCOPE_AGENT);
        unsigned long long v1 = __hip_atomic_load(hp + tid + NTHR,
            __ATOMIC_RELAXED, __HIP_MEMORY_SCOPE_AGENT);
        for (;;) {
            const bool r0 = (((unsigned)v0 & 0xFFu) == exp8) &&
                            (((unsigned)(v0 >> 32) & 0xFFu) == exp8);
            const bool r1 = (((unsigned)v1 & 0xFFu) == exp8) &&
                            (((unsigned)(v1 >> 32) & 0xFFu) == exp8);
            if (r0 && r1) break;
            __builtin_amdgcn_s_sleep(1);
            if (!r0) v0 = __hip_atomic_load(hp + tid,
                __ATOMIC_RELAXED, __HIP_MEMORY_SCOPE_AGENT);
            if (!r1) v1 = __hip_atomic_load(hp + tid + NTHR,
                __ATOMIC_RELAXED, __HIP_MEMORY_SCOPE_AGENT);
        }
        hlds[sp][o0]     = __uint_as_float((unsigned)v0 & 0xFFFFFF00u);
        hlds[sp][o0 + 1] = __uint_as_float((unsigned)(v0 >> 32) & 0xFFFFFF00u);
        hlds[sp][o1]     = __uint_as_float((unsigned)v1 & 0xFFFFFF00u);
        hlds[sp][o1 + 1] = __uint_as_float((unsigned)(v1 >> 32) & 0xFFFFFF00u);
        __syncthreads();

        const float* hc = &hlds[sp][36 * lane];
        float4 hv[8];
#pragma unroll
        for (int k = 0; k < 8; ++k) hv[k] = *(const float4*)(hc + 4 * k);
        for (int r = wave; r < NCLS; r += 8) {
            const float* wr = Wout + (size_t)r * HDIM + 32 * lane;
            float s = 0.f;
#pragma unroll
            for (int k = 0; k < 8; ++k) {
                const float4 wv = *(const float4*)(wr + 4 * k);
                s += wv.x * hv[k].x + wv.y * hv[k].y
                   + wv.z * hv[k].z + wv.w * hv[k].w;
            }
#pragma unroll
            for (int st = 1; st < 64; st <<= 1) s += __shfl_xor(s, st, 64);
            if (lane == 0) lsm[r] = s + bout[r];
        }
        __syncthreads();
        if (tid == 0) {
            float m = lsm[0];
            for (int r = 1; r < NCLS; ++r) m = fmaxf(m, lsm[r]);
            float ex[NCLS];
            float den = 0.0f;
            for (int r = 0; r < NCLS; ++r) { ex[r] = expf(lsm[r] - m); den += ex[r]; }
            const float inv = 1.0f / den;
            for (int r = 0; r < NCLS; ++r) out[r] = ex[r] * inv;
        }
    }
}

extern "C" void kernel_launch(void* const* d_in, const int* in_sizes, int n_in,
                              void* d_out, int out_size, void* d_ws, size_t ws_size,
                              hipStream_t stream) {
    const float* x0    = (const float*)d_in[0];   // row 0 of inputs
    const float* Wih   = (const float*)d_in[1];
    const float* Whh   = (const float*)d_in[2];
    const float* bih   = (const float*)d_in[3];
    const float* bhh   = (const float*)d_in[4];
    const float* Wout  = (const float*)d_in[5];
    const float* bout  = (const float*)d_in[6];
    const int*   steps = (const int*)d_in[7];
    float* out = (float*)d_out;

    unsigned long long* hpub0 = (unsigned long long*)d_ws;
    unsigned long long* hpub1 = hpub0 + NPAIR;

    // init tag bytes to 0xFF (matches no tag value ever written; steps<=512)
    hipMemsetAsync(d_ws, 0xFF, (size_t)2 * NPAIR * sizeof(unsigned long long),
                   stream);

    lstm_persistent<<<dim3(NBLK), dim3(NTHR), 0, stream>>>(
        x0, Wih, Whh, bih, bhh, Wout, bout, steps, out, hpub0, hpub1);
}

// Round 11
// 3539.246 us; speedup vs baseline: 1.5087x; 1.5087x over previous
//
#include <hip/hip_runtime.h>
#include <cstdint>
#include <cstddef>

#define HDIM 2048
#define NCLS 11
#define NBLK 256
#define NTHR 256
#define CHUNK 256               // h-columns per lane (weights in VGPR/AGPR)
#define CPAD  260               // padded chunk stride in LDS floats
#define NPAIR (HDIM / 2)        // 1024 u64 pairs, pair q = elems {2q, 2q+1}

// Exchange: hpub[2][1024] u64; each u64 = two f32 h whose LOW 8 MANTISSA
// BITS hold tag = (gen>>1)&0xFF (RN-rounded, rel err <= 2^-16; R10 measured
// absmax 2.4e-4 << 1.86e-3). gen g lives in buffer g&1; with 0xFF memset and
// steps<=512 the (buffer,tag) pair uniquely identifies gen. SINGLE-HOP: the
// polled load IS the data; each 4B word self-validates, so the two coherent
// dwordx4 loads per thread need no atomicity. sc0 sc1 = bypass L1+L2 to the
// coherence point (same path compiler emits for agent atomics -> liveness).
// Zero fences anywhere (R6: fences = L2 nukes, ~15us/step). 2 outstanding
// requests/thread (R7/R8: 8 outstanding congests the IFC queue).
// Geometry: 256 blocks x 256 threads (R10: 128x512 left half the CUs idle
// and doubled per-SIMD time-sharing -> keep 1 block/CU, 1 wave/SIMD).

__device__ __forceinline__ float waveReduceSum(float v) {
#pragma unroll
    for (int off = 32; off > 0; off >>= 1) v += __shfl_xor(v, off, 64);
    return v;
}

__device__ __forceinline__ void load2_u128(const unsigned long long* p,
                                           uint4& a, uint4& b) {
    asm volatile(
        "global_load_dwordx4 %0, %2, off sc0 sc1\n\t"
        "global_load_dwordx4 %1, %3, off sc0 sc1\n\t"
        "s_waitcnt vmcnt(0)"
        : "=&v"(a), "=&v"(b)
        : "v"(p), "v"(p + 2)
        : "memory");
}

__device__ __forceinline__ bool tags_ok(const uint4& a, unsigned e8) {
    return ((((a.x ^ e8) | (a.y ^ e8) | (a.z ^ e8) | (a.w ^ e8)) & 0xFFu) == 0u);
}

// Weight-stationary persistent LSTM, single-atom tagged-h exchange.
// Block b owns h[b*8..b*8+8). Wave w owns elements {b*8+2w, b*8+2w+1}, all 4
// gates: lane (rl=lane>>3, cc=lane&7) computes row gate(rl&3) of element
// eloc(rl>>2), columns [cc*256, cc*256+256) held in registers.
__global__ void __launch_bounds__(NTHR, 1) lstm_persistent(
    const float* __restrict__ x0,
    const float* __restrict__ Wih,
    const float* __restrict__ Whh,
    const float* __restrict__ bih,
    const float* __restrict__ bhh,
    const float* __restrict__ Wout,
    const float* __restrict__ bout,
    const int* __restrict__ stepsp,
    float* __restrict__ out,
    unsigned long long* __restrict__ hpub0,
    unsigned long long* __restrict__ hpub1)
{
    const int tid  = threadIdx.x;
    const int wave = tid >> 6;
    const int lane = tid & 63;
    const int rl   = lane >> 3;         // 0..7
    const int cc   = lane & 7;          // column chunk
    const int gate = rl & 3;            // i,f,g,o
    const int eloc = rl >> 2;           // 0..1 within wave
    const int bid  = blockIdx.x;
    const int elem = bid * 8 + 2 * wave + eloc;   // h element this lane serves

    __shared__ float hlds[2][8 * CPAD];

    const int row = gate * HDIM + elem;
    const size_t sbase = (size_t)row * HDIM + (size_t)cc * CHUNK;

    // prefill: w = W_ih slice (step 0 uses W_ih alone since h0 = 0)
    float w[CHUNK];
#pragma unroll
    for (int jj = 0; jj < 64; ++jj) {
        float4 v = *(const float4*)(Wih + sbase + (size_t)jj * 4);
        w[4 * jj + 0] = v.x; w[4 * jj + 1] = v.y;
        w[4 * jj + 2] = v.z; w[4 * jj + 3] = v.w;
    }
    const float bsum = bih[row] + bhh[row];
    float creg = 0.0f, hreg = 0.0f;

    const int steps = stepsp[0];
    const int e0   = tid * 8;                              // elems this thread stages
    const int soff = (tid >> 5) * CPAD + (tid & 31) * 8;   // LDS addr (16B aligned)
    const int pub_pair = bid * 4 + wave;                   // pair of elems {2w,2w+1}

    for (int t = 0; t < steps; ++t) {
        const int p = t & 1;
        if (t == 0) {
            float4 a = *(const float4*)(x0 + e0);
            float4 b = *(const float4*)(x0 + e0 + 4);
            *(float4*)&hlds[0][soff]     = a;
            *(float4*)&hlds[0][soff + 4] = b;
        } else {
            const unsigned e8 = (unsigned)(t >> 1) & 0xFFu;
            const unsigned long long* pp = (p ? hpub1 : hpub0) + 4 * tid;
            uint4 a, b;
            load2_u128(pp, a, b);
            while (!(tags_ok(a, e8) && tags_ok(b, e8))) {
                __builtin_amdgcn_s_sleep(1);
                load2_u128(pp, a, b);
            }
            float4 fa, fb;      // strip tags
            fa.x = __uint_as_float(a.x & 0xFFFFFF00u);
            fa.y = __uint_as_float(a.y & 0xFFFFFF00u);
            fa.z = __uint_as_float(a.z & 0xFFFFFF00u);
            fa.w = __uint_as_float(a.w & 0xFFFFFF00u);
            fb.x = __uint_as_float(b.x & 0xFFFFFF00u);
            fb.y = __uint_as_float(b.y & 0xFFFFFF00u);
            fb.z = __uint_as_float(b.z & 0xFFFFFF00u);
            fb.w = __uint_as_float(b.w & 0xFFFFFF00u);
            *(float4*)&hlds[p][soff]     = fa;
            *(float4*)&hlds[p][soff + 4] = fb;
        }
        __syncthreads();     // sole per-step barrier (hlds double-buffered)

        // dot: 256 register weights x LDS-broadcast h chunk
        const float* hc = &hlds[p][cc * CPAD];
        float ax = 0.f, ay = 0.f, az = 0.f, aw = 0.f;
#pragma unroll
        for (int jj = 0; jj < 64; ++jj) {
            float4 hv = *(const float4*)(hc + jj * 4);
            ax += w[4 * jj + 0] * hv.x;
            ay += w[4 * jj + 1] * hv.y;
            az += w[4 * jj + 2] * hv.z;
            aw += w[4 * jj + 3] * hv.w;
        }
        float part = (ax + ay) + (az + aw);
        part += __shfl_xor(part, 1, 64);
        part += __shfl_xor(part, 2, 64);
        part += __shfl_xor(part, 4, 64);        // all 8 lanes: row total
        part += bsum;

        // gather the 4 gate rows of this lane's element (wave-local)
        const int sb = (lane & 0x20) | (lane & 7);
        float gi = __shfl(part, sb + 0,  64);
        float gf = __shfl(part, sb + 8,  64);
        float gg = __shfl(part, sb + 16, 64);
        float go = __shfl(part, sb + 24, 64);

        float si = 1.0f / (1.0f + expf(-gi));
        float sf = 1.0f / (1.0f + expf(-gf));
        float tg = tanhf(gg);
        float so = 1.0f / (1.0f + expf(-go));
        creg = sf * creg + si * tg;             // consistent across the 32 lanes
        hreg = so * tanhf(creg);

        // pair the two half-wave h values, publish one tagged u64 from lane 0
        const float hOther = __shfl_xor(hreg, 32, 64);
        if (lane == 0) {
            const unsigned t8 = ((unsigned)(t + 1) >> 1) & 0xFFu;
            const unsigned u0 =
                ((__float_as_uint(hreg) + 0x80u) & 0xFFFFFF00u) | t8;
            const unsigned u1 =
                ((__float_as_uint(hOther) + 0x80u) & 0xFFFFFF00u) | t8;
            const unsigned long long pk =
                ((unsigned long long)u1 << 32) | (unsigned long long)u0;
            __hip_atomic_store((((t + 1) & 1) ? hpub1 : hpub0) + pub_pair, pk,
                               __ATOMIC_RELAXED, __HIP_MEMORY_SCOPE_AGENT);
        }

        if (t == 0) {
            // switch weights to Wc = W_ih + W_hh for steps >= 1
#pragma unroll
            for (int jj = 0; jj < 64; ++jj) {
                float4 v = *(const float4*)(Whh + sbase + (size_t)jj * 4);
                w[4 * jj + 0] += v.x; w[4 * jj + 1] += v.y;
                w[4 * jj + 2] += v.z; w[4 * jj + 3] += v.w;
            }
        }
    }

    // final h and c straight from registers (disjoint across blocks/waves)
    if ((lane & 31) == 0) {
        out[NCLS + elem]        = hreg;
        out[NCLS + HDIM + elem] = creg;
    }

    // block 0: gather final h (gen == steps), classifier head
    if (bid == 0) {
        __syncthreads();        // all waves past the loop before hlds reuse
        const int sp = steps & 1;
        const unsigned e8 = (unsigned)(steps >> 1) & 0xFFu;
        const unsigned long long* pp = (sp ? hpub1 : hpub0) + 4 * tid;
        uint4 a, b;
        load2_u128(pp, a, b);
        while (!(tags_ok(a, e8) && tags_ok(b, e8))) {
            __builtin_amdgcn_s_sleep(1);
            load2_u128(pp, a, b);
        }
        hlds[0][soff + 0] = __uint_as_float(a.x & 0xFFFFFF00u);
        hlds[0][soff + 1] = __uint_as_float(a.y & 0xFFFFFF00u);
        hlds[0][soff + 2] = __uint_as_float(a.z & 0xFFFFFF00u);
        hlds[0][soff + 3] = __uint_as_float(a.w & 0xFFFFFF00u);
        hlds[0][soff + 4] = __uint_as_float(b.x & 0xFFFFFF00u);
        hlds[0][soff + 5] = __uint_as_float(b.y & 0xFFFFFF00u);
        hlds[0][soff + 6] = __uint_as_float(b.z & 0xFFFFFF00u);
        hlds[0][soff + 7] = __uint_as_float(b.w & 0xFFFFFF00u);
        __syncthreads();

        __shared__ float lsm[NCLS];
        float hr[8][4];
#pragma unroll
        for (int k = 0; k < 8; ++k)
#pragma unroll
            for (int c = 0; c < 4; ++c)
                hr[k][c] = hlds[0][k * CPAD + lane * 4 + c];
        for (int r = wave; r < NCLS; r += 4) {
            const float4* w4 = (const float4*)(Wout + (size_t)r * HDIM);
            float sx = 0.f, sy = 0.f, sz = 0.f, sw4 = 0.f;
#pragma unroll
            for (int k = 0; k < 8; ++k) {
                float4 wv = w4[k * 64 + lane];
                sx  += wv.x * hr[k][0];
                sy  += wv.y * hr[k][1];
                sz  += wv.z * hr[k][2];
                sw4 += wv.w * hr[k][3];
            }
            float s = waveReduceSum((sx + sy) + (sz + sw4));
            if (lane == 0) lsm[r] = s + bout[r];
        }
        __syncthreads();
        if (tid == 0) {
            float m = lsm[0];
            for (int r = 1; r < NCLS; ++r) m = fmaxf(m, lsm[r]);
            float ex[NCLS];
            float den = 0.0f;
            for (int r = 0; r < NCLS; ++r) { ex[r] = expf(lsm[r] - m); den += ex[r]; }
            const float inv = 1.0f / den;
            for (int r = 0; r < NCLS; ++r) out[r] = ex[r] * inv;
        }
    }
}

extern "C" void kernel_launch(void* const* d_in, const int* in_sizes, int n_in,
                              void* d_out, int out_size, void* d_ws, size_t ws_size,
                              hipStream_t stream) {
    const float* x0    = (const float*)d_in[0];   // row 0 of inputs
    const float* Wih   = (const float*)d_in[1];
    const float* Whh   = (const float*)d_in[2];
    const float* bih   = (const float*)d_in[3];
    const float* bhh   = (const float*)d_in[4];
    const float* Wout  = (const float*)d_in[5];
    const float* bout  = (const float*)d_in[6];
    const int*   steps = (const int*)d_in[7];
    float* out = (float*)d_out;

    unsigned long long* hpub0 = (unsigned long long*)d_ws;
    unsigned long long* hpub1 = hpub0 + NPAIR;

    // init tag bytes to 0xFF (matches no tag value ever written; steps<=512)
    hipMemsetAsync(d_ws, 0xFF, (size_t)2 * NPAIR * sizeof(unsigned long long),
                   stream);

    lstm_persistent<<<dim3(NBLK), dim3(NTHR), 0, stream>>>(
        x0, Wih, Whh, bih, bhh, Wout, bout, steps, out, hpub0, hpub1);
}

// Round 14
// 2541.571 us; speedup vs baseline: 2.1010x; 1.3925x over previous
//
#include <hip/hip_runtime.h>
#include <cstdint>
#include <cstddef>

#define HDIM 2048
#define NCLS 11
#define NBLK 256
#define NTHR 256
#define CHUNK 256               // h-columns per lane (weights in VGPR/AGPR)
#define CPAD  260               // padded chunk stride in LDS floats

// d_ws: two generation-tagged h-slot buffers (parity = step & 1).
// Slot b (64 B, sw=16): { h[8] f32, gen u32, pad }. memset each launch.
// Protocol (R6-proven, 3.00 ms): ALL cross-block traffic is device-coherent
// (relaxed agent atomics / sc0 sc1 loads served at the coherence point).
// Producer: 8 h stores -> __syncthreads (vmcnt drain orders them) -> gen
// store. Consumer: spin on gen (1 outstanding poll/thread), compiler
// barrier, then read h. ZERO fences (R6: fences = L2 nukes, ~15 us/step).
// R12 lesson: never spin on sc0-only (XCD-local) state - liveness must not
// depend on the block->XCD mapping. R6->R14 delta: the 8 scalar post-tag h
// loads become TWO dwordx4 sc0 sc1 loads (R11-proven helper): 4x fewer IFC
// transactions on the serial chain.

__device__ __forceinline__ float waveReduceSum(float v) {
#pragma unroll
    for (int off = 32; off > 0; off >>= 1) v += __shfl_xor(v, off, 64);
    return v;
}

// two coherent 16B loads from one 64B slot (device-scope, bypasses L1/L2)
__device__ __forceinline__ void ifc_load32B(const float* p, float4& a, float4& b) {
    asm volatile(
        "global_load_dwordx4 %0, %2, off sc0 sc1\n\t"
        "global_load_dwordx4 %1, %3, off sc0 sc1\n\t"
        "s_waitcnt vmcnt(0)"
        : "=&v"(a), "=&v"(b) : "v"(p), "v"(p + 4) : "memory");
}

// Weight-stationary persistent LSTM, fence-free gen-tagged h exchange.
// Block b owns h[b*8..b*8+8); wave w = gate w; lane (rl=lane>>3, cc=lane&7)
// owns row w*2048+b*8+rl, columns [cc*256, cc*256+256) held in registers.
__global__ void __launch_bounds__(NTHR, 1) lstm_persistent(
    const float* __restrict__ x0,
    const float* __restrict__ Wih,
    const float* __restrict__ Whh,
    const float* __restrict__ bih,
    const float* __restrict__ bhh,
    const float* __restrict__ Wout,
    const float* __restrict__ bout,
    const int* __restrict__ stepsp,
    float* __restrict__ out,
    float* __restrict__ tag0,
    float* __restrict__ tag1,
    int sw)                      // slot stride in floats (>= 9)
{
    const int tid  = threadIdx.x;
    const int wave = tid >> 6;          // gate (i,f,g,o)
    const int lane = tid & 63;
    const int rl   = lane >> 3;         // row within gate for this block
    const int cc   = lane & 7;          // column chunk
    const int bid  = blockIdx.x;
    const int jb   = bid * 8;           // first h element owned by this block

    __shared__ float hlds[2][8 * CPAD];
    __shared__ float gsm[4 * 8];
    __shared__ float csm[8];

    const int row = wave * HDIM + jb + rl;
    const size_t sbase = (size_t)row * HDIM + (size_t)cc * CHUNK;

    // prefill: w = W_ih slice (step 0 uses W_ih alone since h0 = 0)
    float w[CHUNK];
#pragma unroll
    for (int jj = 0; jj < 64; ++jj) {
        float4 v = *(const float4*)(Wih + sbase + (size_t)jj * 4);
        w[4 * jj + 0] = v.x; w[4 * jj + 1] = v.y;
        w[4 * jj + 2] = v.z; w[4 * jj + 3] = v.w;
    }
    const float bsum = bih[row] + bhh[row];
    if (tid < 8) csm[tid] = 0.0f;
    __syncthreads();

    const int steps = stepsp[0];
    const int e0   = tid * 8;                              // h elems this thread stages
    const int soff = (tid >> 5) * CPAD + (tid & 31) * 8;   // LDS address of e0
    const bool vec = (sw == 16);                           // 64B-aligned slots

    for (int t = 0; t < steps; ++t) {
        const int p = t & 1;
        if (t == 0) {
#pragma unroll
            for (int i = 0; i < 8; ++i) hlds[0][soff + i] = x0[e0 + i];
        } else {
            float* tb   = p ? tag1 : tag0;
            float* slot = tb + (size_t)tid * sw;            // producer block tid's slot
            unsigned* genp = (unsigned*)(slot + 8);
            while (__hip_atomic_load(genp, __ATOMIC_RELAXED, __HIP_MEMORY_SCOPE_AGENT)
                   < (unsigned)t)
                __builtin_amdgcn_s_sleep(1);
            asm volatile("" ::: "memory");   // no load hoisting above the spin
            if (vec) {
                float4 a, b;
                ifc_load32B(slot, a, b);
                *(float4*)&hlds[p][soff]     = a;
                *(float4*)&hlds[p][soff + 4] = b;
            } else {
#pragma unroll
                for (int i = 0; i < 8; ++i)
                    hlds[p][soff + i] = __hip_atomic_load(slot + i, __ATOMIC_RELAXED,
                                                          __HIP_MEMORY_SCOPE_AGENT);
            }
        }
        __syncthreads();     // sole steady-state barrier pre-compute (hlds dbuf)

        // dot: 256 register weights x LDS-broadcast h chunk
        const float* hc = &hlds[p][cc * CPAD];
        float ax = 0.f, ay = 0.f, az = 0.f, aw = 0.f;
#pragma unroll
        for (int jj = 0; jj < 64; ++jj) {
            float4 hv = *(const float4*)(hc + jj * 4);
            ax += w[4 * jj + 0] * hv.x;
            ay += w[4 * jj + 1] * hv.y;
            az += w[4 * jj + 2] * hv.z;
            aw += w[4 * jj + 3] * hv.w;
        }
        float part = (ax + ay) + (az + aw);
        part += __shfl_xor(part, 1, 64);
        part += __shfl_xor(part, 2, 64);
        part += __shfl_xor(part, 4, 64);        // summed over cc
        if (cc == 0) gsm[wave * 8 + rl] = part + bsum;
        __syncthreads();

        float* wbuf = ((t + 1) & 1) ? tag1 : tag0;
        float* wslot = wbuf + (size_t)bid * sw;
        if (tid < 8) {
            float gi = gsm[0 * 8 + tid];
            float gf = gsm[1 * 8 + tid];
            float gg = gsm[2 * 8 + tid];
            float go = gsm[3 * 8 + tid];
            float si = 1.0f / (1.0f + expf(-gi));
            float sf = 1.0f / (1.0f + expf(-gf));
            float tg = tanhf(gg);
            float so = 1.0f / (1.0f + expf(-go));
            float c  = sf * csm[tid] + si * tg;
            csm[tid] = c;
            __hip_atomic_store(wslot + tid, so * tanhf(c),
                               __ATOMIC_RELAXED, __HIP_MEMORY_SCOPE_AGENT);
        }
        __syncthreads();   // vmcnt(0) drain: h stores at coherence point before tag
        if (tid == 0)
            __hip_atomic_store((unsigned*)(wslot + 8), (unsigned)(t + 1),
                               __ATOMIC_RELAXED, __HIP_MEMORY_SCOPE_AGENT);

        if (t == 0) {
            // switch weights to Wc = W_ih + W_hh for steps >= 1
#pragma unroll
            for (int jj = 0; jj < 64; ++jj) {
                float4 v = *(const float4*)(Whh + sbase + (size_t)jj * 4);
                w[4 * jj + 0] += v.x; w[4 * jj + 1] += v.y;
                w[4 * jj + 2] += v.z; w[4 * jj + 3] += v.w;
            }
        }
    }

    // final c
    if (tid < 8) out[NCLS + HDIM + jb + tid] = csm[tid];

    // block 0: gather final h (gen == steps), classifier head + h copy
    if (bid == 0) {
        float* tb   = (steps & 1) ? tag1 : tag0;
        float* slot = tb + (size_t)tid * sw;
        unsigned* genp = (unsigned*)(slot + 8);
        while (__hip_atomic_load(genp, __ATOMIC_RELAXED, __HIP_MEMORY_SCOPE_AGENT)
               < (unsigned)steps)
            __builtin_amdgcn_s_sleep(1);
        asm volatile("" ::: "memory");
        if (vec) {
            float4 a, b;
            ifc_load32B(slot, a, b);
            *(float4*)&hlds[0][soff]     = a;
            *(float4*)&hlds[0][soff + 4] = b;
        } else {
#pragma unroll
            for (int i = 0; i < 8; ++i)
                hlds[0][soff + i] = __hip_atomic_load(slot + i, __ATOMIC_RELAXED,
                                                      __HIP_MEMORY_SCOPE_AGENT);
        }
        __syncthreads();

        __shared__ float lsm[NCLS];
        float hr[8][4];
#pragma unroll
        for (int k = 0; k < 8; ++k)
#pragma unroll
            for (int c = 0; c < 4; ++c)
                hr[k][c] = hlds[0][k * CPAD + lane * 4 + c];
        for (int r = wave; r < NCLS; r += 4) {
            const float4* w4 = (const float4*)(Wout + (size_t)r * HDIM);
            float sx = 0.f, sy = 0.f, sz = 0.f, sw4 = 0.f;
#pragma unroll
            for (int k = 0; k < 8; ++k) {
                float4 wv = w4[k * 64 + lane];
                sx  += wv.x * hr[k][0];
                sy  += wv.y * hr[k][1];
                sz  += wv.z * hr[k][2];
                sw4 += wv.w * hr[k][3];
            }
            float s = waveReduceSum((sx + sy) + (sz + sw4));
            if (lane == 0) lsm[r] = s + bout[r];
        }
        __syncthreads();
        if (tid == 0) {
            float m = lsm[0];
            for (int r = 1; r < NCLS; ++r) m = fmaxf(m, lsm[r]);
            float ex[NCLS];
            float den = 0.0f;
            for (int r = 0; r < NCLS; ++r) { ex[r] = expf(lsm[r] - m); den += ex[r]; }
            float inv = 1.0f / den;
            for (int r = 0; r < NCLS; ++r) out[r] = ex[r] * inv;
        }
#pragma unroll
        for (int i = 0; i < 8; ++i)
            out[NCLS + e0 + i] = hlds[0][soff + i];
    }
}

extern "C" void kernel_launch(void* const* d_in, const int* in_sizes, int n_in,
                              void* d_out, int out_size, void* d_ws, size_t ws_size,
                              hipStream_t stream) {
    const float* x0    = (const float*)d_in[0];   // row 0 of inputs
    const float* Wih   = (const float*)d_in[1];
    const float* Whh   = (const float*)d_in[2];
    const float* bih   = (const float*)d_in[3];
    const float* bhh   = (const float*)d_in[4];
    const float* Wout  = (const float*)d_in[5];
    const float* bout  = (const float*)d_in[6];
    const int*   steps = (const int*)d_in[7];
    float* out = (float*)d_out;

    // slot stride: 16 floats (64 B, line-aligned) if workspace allows, else 9
    int sw = 16;
    size_t need = (size_t)2 * NBLK * sw * sizeof(float);   // 32 KiB
    if (ws_size < need) { sw = 9; need = (size_t)2 * NBLK * sw * sizeof(float); }

    float* tag0 = (float*)d_ws;
    float* tag1 = tag0 + (size_t)NBLK * sw;

    // reset generation tags each launch (graph-capture safe, deterministic)
    (void)hipMemsetAsync(d_ws, 0, need, stream);

    lstm_persistent<<<dim3(NBLK), dim3(NTHR), 0, stream>>>(
        x0, Wih, Whh, bih, bhh, Wout, bout, steps, out, tag0, tag1, sw);
}

// Round 15
// 2435.089 us; speedup vs baseline: 2.1928x; 1.0437x over previous
//
#include <hip/hip_runtime.h>
#include <cstdint>
#include <cstddef>

#define HDIM 2048
#define NCLS 11
#define NBLK 256
#define NTHR 256
#define CHUNK 256               // h-columns per lane (weights in VGPR/AGPR)
#define CPAD  260               // padded chunk stride in LDS floats

// d_ws: two h-slot buffers (parity = gen & 1), slot b = 64 B (sw=16):
// 8 f32 h values whose LOW 8 MANTISSA BITS hold tag=(gen>>1)&0xFF
// (RN-rounded; R10/R11: absmax 2.44e-4 << 1.86e-3 threshold; (parity,tag)
// uniquely identifies gen for steps<=512; memset 0xFF aliases no first-use).
// Protocol (R6/R14-proven + tag fusion): producer tid<8 publishes ONE
// coalesced 32B store of self-tagged h - no barrier, no separate tag store.
// Consumer: scalar-poll word 0 only (1 outstanding 4B load - R7/R8/R11:
// heavy polls congest the IFC), on hit ONE 32B sc0sc1 burst, validate all
// 8 embedded tags, rare retry. ZERO fences (R6: fences = L2 nukes).
// WAR-liveness: block B overwrites a parity slot (gen t+1 over t-1) only
// after staging gen t from ALL blocks => every block consumed gen t-1.

__device__ __forceinline__ float waveReduceSum(float v) {
#pragma unroll
    for (int off = 32; off > 0; off >>= 1) v += __shfl_xor(v, off, 64);
    return v;
}

// two coherent 16B loads from one 64B slot (device-scope, bypasses L1/L2)
__device__ __forceinline__ void ifc_load32B(const float* p, uint4& a, uint4& b) {
    asm volatile(
        "global_load_dwordx4 %0, %2, off sc0 sc1\n\t"
        "global_load_dwordx4 %1, %3, off sc0 sc1\n\t"
        "s_waitcnt vmcnt(0)"
        : "=&v"(a), "=&v"(b) : "v"(p), "v"(p + 4) : "memory");
}

__device__ __forceinline__ bool tags_ok(const uint4& a, unsigned e8) {
    return ((((a.x ^ e8) | (a.y ^ e8) | (a.z ^ e8) | (a.w ^ e8)) & 0xFFu) == 0u);
}

// Weight-stationary persistent LSTM, self-tagged single-store h exchange.
// Block b owns h[b*8..b*8+8); wave w = gate w; lane (rl=lane>>3, cc=lane&7)
// owns row w*2048+b*8+rl, columns [cc*256, cc*256+256) held in registers.
__global__ void __launch_bounds__(NTHR, 1) lstm_persistent(
    const float* __restrict__ x0,
    const float* __restrict__ Wih,
    const float* __restrict__ Whh,
    const float* __restrict__ bih,
    const float* __restrict__ bhh,
    const float* __restrict__ Wout,
    const float* __restrict__ bout,
    const int* __restrict__ stepsp,
    float* __restrict__ out,
    float* __restrict__ tag0,
    float* __restrict__ tag1)
{
    const int tid  = threadIdx.x;
    const int wave = tid >> 6;          // gate (i,f,g,o)
    const int lane = tid & 63;
    const int rl   = lane >> 3;         // row within gate for this block
    const int cc   = lane & 7;          // column chunk
    const int bid  = blockIdx.x;
    const int jb   = bid * 8;           // first h element owned by this block

    __shared__ float hlds[2][8 * CPAD];
    __shared__ float gsm[4 * 8];
    __shared__ float csm[8];

    const int row = wave * HDIM + jb + rl;
    const size_t sbase = (size_t)row * HDIM + (size_t)cc * CHUNK;

    // prefill: w = W_ih slice (step 0 uses W_ih alone since h0 = 0)
    float w[CHUNK];
#pragma unroll
    for (int jj = 0; jj < 64; ++jj) {
        float4 v = *(const float4*)(Wih + sbase + (size_t)jj * 4);
        w[4 * jj + 0] = v.x; w[4 * jj + 1] = v.y;
        w[4 * jj + 2] = v.z; w[4 * jj + 3] = v.w;
    }
    const float bsum = bih[row] + bhh[row];
    if (tid < 8) csm[tid] = 0.0f;
    __syncthreads();

    const int steps = stepsp[0];
    const int e0   = tid * 8;                              // h elems this thread stages
    const int soff = (tid >> 5) * CPAD + (tid & 31) * 8;   // LDS address of e0

    for (int t = 0; t < steps; ++t) {
        const int p = t & 1;
        if (t == 0) {
#pragma unroll
            for (int i = 0; i < 8; ++i) hlds[0][soff + i] = x0[e0 + i];
        } else {
            const unsigned e8 = (unsigned)(t >> 1) & 0xFFu;
            float* slot = (p ? tag1 : tag0) + (size_t)tid * 16;  // producer tid's slot
            // scalar poll on word 0 (1 outstanding 4B request)
            while (((__hip_atomic_load((const unsigned*)slot, __ATOMIC_RELAXED,
                                       __HIP_MEMORY_SCOPE_AGENT) ^ e8) & 0xFFu) != 0u)
                __builtin_amdgcn_s_sleep(1);
            asm volatile("" ::: "memory");   // no hoisting above the spin
            uint4 a, b;
            ifc_load32B(slot, a, b);
            while (!(tags_ok(a, e8) && tags_ok(b, e8))) {   // rare partial store
                __builtin_amdgcn_s_sleep(1);
                ifc_load32B(slot, a, b);
            }
            float4 fa, fb;      // strip tags
            fa.x = __uint_as_float(a.x & 0xFFFFFF00u);
            fa.y = __uint_as_float(a.y & 0xFFFFFF00u);
            fa.z = __uint_as_float(a.z & 0xFFFFFF00u);
            fa.w = __uint_as_float(a.w & 0xFFFFFF00u);
            fb.x = __uint_as_float(b.x & 0xFFFFFF00u);
            fb.y = __uint_as_float(b.y & 0xFFFFFF00u);
            fb.z = __uint_as_float(b.z & 0xFFFFFF00u);
            fb.w = __uint_as_float(b.w & 0xFFFFFF00u);
            *(float4*)&hlds[p][soff]     = fa;
            *(float4*)&hlds[p][soff + 4] = fb;
        }
        __syncthreads();     // staging complete (hlds double-buffered)

        // dot: 256 register weights x LDS-broadcast h chunk
        const float* hc = &hlds[p][cc * CPAD];
        float ax = 0.f, ay = 0.f, az = 0.f, aw = 0.f;
#pragma unroll
        for (int jj = 0; jj < 64; ++jj) {
            float4 hv = *(const float4*)(hc + jj * 4);
            ax += w[4 * jj + 0] * hv.x;
            ay += w[4 * jj + 1] * hv.y;
            az += w[4 * jj + 2] * hv.z;
            aw += w[4 * jj + 3] * hv.w;
        }
        float part = (ax + ay) + (az + aw);
        part += __shfl_xor(part, 1, 64);
        part += __shfl_xor(part, 2, 64);
        part += __shfl_xor(part, 4, 64);        // summed over cc
        if (cc == 0) gsm[wave * 8 + rl] = part + bsum;
        __syncthreads();

        // pointwise + single coalesced self-tagged publish (no barrier after)
        float* wslot = (((t + 1) & 1) ? tag1 : tag0) + (size_t)bid * 16;
        if (tid < 8) {
            float gi = gsm[0 * 8 + tid];
            float gf = gsm[1 * 8 + tid];
            float gg = gsm[2 * 8 + tid];
            float go = gsm[3 * 8 + tid];
            float si = 1.0f / (1.0f + expf(-gi));
            float sf = 1.0f / (1.0f + expf(-gf));
            float tg = tanhf(gg);
            float so = 1.0f / (1.0f + expf(-go));
            float c  = sf * csm[tid] + si * tg;
            csm[tid] = c;
            const float h = so * tanhf(c);
            const unsigned t8 = ((unsigned)(t + 1) >> 1) & 0xFFu;
            const unsigned uv = ((__float_as_uint(h) + 0x80u) & 0xFFFFFF00u) | t8;
            __hip_atomic_store((unsigned*)wslot + tid, uv,
                               __ATOMIC_RELAXED, __HIP_MEMORY_SCOPE_AGENT);
        }

        if (t == 0) {
            // switch weights to Wc = W_ih + W_hh for steps >= 1
#pragma unroll
            for (int jj = 0; jj < 64; ++jj) {
                float4 v = *(const float4*)(Whh + sbase + (size_t)jj * 4);
                w[4 * jj + 0] += v.x; w[4 * jj + 1] += v.y;
                w[4 * jj + 2] += v.z; w[4 * jj + 3] += v.w;
            }
        }
    }

    // final c (exact, from LDS-resident state)
    if (tid < 8) out[NCLS + HDIM + jb + tid] = csm[tid];

    // block 0: gather final h (gen == steps), classifier head + h copy
    if (bid == 0) {
        const int sp = steps & 1;
        const unsigned e8 = (unsigned)(steps >> 1) & 0xFFu;
        float* slot = (sp ? tag1 : tag0) + (size_t)tid * 16;
        while (((__hip_atomic_load((const unsigned*)slot, __ATOMIC_RELAXED,
                                   __HIP_MEMORY_SCOPE_AGENT) ^ e8) & 0xFFu) != 0u)
            __builtin_amdgcn_s_sleep(1);
        asm volatile("" ::: "memory");
        uint4 a, b;
        ifc_load32B(slot, a, b);
        while (!(tags_ok(a, e8) && tags_ok(b, e8))) {
            __builtin_amdgcn_s_sleep(1);
            ifc_load32B(slot, a, b);
        }
        hlds[0][soff + 0] = __uint_as_float(a.x & 0xFFFFFF00u);
        hlds[0][soff + 1] = __uint_as_float(a.y & 0xFFFFFF00u);
        hlds[0][soff + 2] = __uint_as_float(a.z & 0xFFFFFF00u);
        hlds[0][soff + 3] = __uint_as_float(a.w & 0xFFFFFF00u);
        hlds[0][soff + 4] = __uint_as_float(b.x & 0xFFFFFF00u);
        hlds[0][soff + 5] = __uint_as_float(b.y & 0xFFFFFF00u);
        hlds[0][soff + 6] = __uint_as_float(b.z & 0xFFFFFF00u);
        hlds[0][soff + 7] = __uint_as_float(b.w & 0xFFFFFF00u);
        __syncthreads();

        __shared__ float lsm[NCLS];
        float hr[8][4];
#pragma unroll
        for (int k = 0; k < 8; ++k)
#pragma unroll
            for (int c = 0; c < 4; ++c)
                hr[k][c] = hlds[0][k * CPAD + lane * 4 + c];
        for (int r = wave; r < NCLS; r += 4) {
            const float4* w4 = (const float4*)(Wout + (size_t)r * HDIM);
            float sx = 0.f, sy = 0.f, sz = 0.f, sw4 = 0.f;
#pragma unroll
            for (int k = 0; k < 8; ++k) {
                float4 wv = w4[k * 64 + lane];
                sx  += wv.x * hr[k][0];
                sy  += wv.y * hr[k][1];
                sz  += wv.z * hr[k][2];
                sw4 += wv.w * hr[k][3];
            }
            float s = waveReduceSum((sx + sy) + (sz + sw4));
            if (lane == 0) lsm[r] = s + bout[r];
        }
        __syncthreads();
        if (tid == 0) {
            float m = lsm[0];
            for (int r = 1; r < NCLS; ++r) m = fmaxf(m, lsm[r]);
            float ex[NCLS];
            float den = 0.0f;
            for (int r = 0; r < NCLS; ++r) { ex[r] = expf(lsm[r] - m); den += ex[r]; }
            float inv = 1.0f / den;
            for (int r = 0; r < NCLS; ++r) out[r] = ex[r] * inv;
        }
#pragma unroll
        for (int i = 0; i < 8; ++i)
            out[NCLS + e0 + i] = hlds[0][soff + i];
    }
}

extern "C" void kernel_launch(void* const* d_in, const int* in_sizes, int n_in,
                              void* d_out, int out_size, void* d_ws, size_t ws_size,
                              hipStream_t stream) {
    const float* x0    = (const float*)d_in[0];   // row 0 of inputs
    const float* Wih   = (const float*)d_in[1];
    const float* Whh   = (const float*)d_in[2];
    const float* bih   = (const float*)d_in[3];
    const float* bhh   = (const float*)d_in[4];
    const float* Wout  = (const float*)d_in[5];
    const float* bout  = (const float*)d_in[6];
    const int*   steps = (const int*)d_in[7];
    float* out = (float*)d_out;

    float* tag0 = (float*)d_ws;
    float* tag1 = tag0 + (size_t)NBLK * 16;

    // tag bytes -> 0xFF: aliases no first-use expectation (t=1 wants 0,
    // t=2 wants 1); later steps overwrite every slot every step.
    (void)hipMemsetAsync(d_ws, 0xFF,
                         (size_t)2 * NBLK * 16 * sizeof(float), stream);

    lstm_persistent<<<dim3(NBLK), dim3(NTHR), 0, stream>>>(
        x0, Wih, Whh, bih, bhh, Wout, bout, steps, out, tag0, tag1);
}